// Round 3
// baseline (451.758 us; speedup 1.0000x reference)
//
#include <hip/hip_runtime.h>
#include <hip/hip_bf16.h>

#define N 8192
#define DIN 128
#define DHID 256
#define DOUT 64
#define LDP 72  // padded LDS row stride (ushorts): 144B -> 4-bank step per row

typedef __attribute__((ext_vector_type(8))) short short8;
typedef __attribute__((ext_vector_type(4))) float f32x4;
typedef __attribute__((ext_vector_type(4))) unsigned short u16x4;

__device__ inline unsigned short f2bf(float x) {
  unsigned u = __float_as_uint(x);
  u += 0x7FFF + ((u >> 16) & 1);   // RNE
  return (unsigned short)(u >> 16);
}
__device__ inline float bf2f(unsigned short u) {
  return __uint_as_float(((unsigned)u) << 16);
}
__device__ inline float sig_clip(float x) {
  float s = 1.0f / (1.0f + __expf(-x));
  return fmaxf(s, 0.1f);
}

// ---------------- K1: BatchNorm statistics ----------------
__global__ void bn_stats(const float* __restrict__ H, const float* __restrict__ bnw,
                         const float* __restrict__ bnb, float* __restrict__ scale,
                         float* __restrict__ shift) {
  int f = blockIdx.x;
  int t = threadIdx.x;
  float s = 0.f, sq = 0.f;
  for (int r = t; r < N; r += 256) {
    float v = H[(size_t)r * DIN + f];
    s += v; sq += v * v;
  }
  __shared__ float ss[256], s2[256];
  ss[t] = s; s2[t] = sq;
  __syncthreads();
  for (int o = 128; o > 0; o >>= 1) {
    if (t < o) { ss[t] += ss[t + o]; s2[t] += s2[t + o]; }
    __syncthreads();
  }
  if (t == 0) {
    float mean = ss[0] * (1.0f / N);
    float var = s2[0] * (1.0f / N) - mean * mean;
    float sc = rsqrtf(var + 1e-5f) * bnw[f];
    scale[f] = sc;
    shift[f] = bnb[f] - mean * sc;
  }
}

// ---------------- K2: Hn -> Hx bf16 [N,256], M2T bf16 [64][N] (transposed) ----------------
__global__ __launch_bounds__(256) void proj(const float* __restrict__ H,
                     const float* __restrict__ scale, const float* __restrict__ shift,
                     const float* __restrict__ Wt, const float* __restrict__ bt,
                     const float* __restrict__ Wo, const float* __restrict__ bo,
                     unsigned short* __restrict__ Hx, unsigned short* __restrict__ M2T) {
  __shared__ float hn[8][DIN];
  int i0 = blockIdx.x * 8;
  int t = threadIdx.x;
  #pragma unroll
  for (int rep = 0; rep < 4; ++rep) {
    int idx = rep * 256 + t;
    int r = idx >> 7, c = idx & 127;
    float h = H[(size_t)(i0 + r) * DIN + c];
    hn[r][c] = fmaf(h, scale[c], shift[c]);
  }
  __syncthreads();
  {
    int c = t;  // 0..255
    float acc[8];
    float b = bt[c];
    #pragma unroll
    for (int r = 0; r < 8; ++r) acc[r] = b;
    for (int k = 0; k < DIN; ++k) {
      float w = Wt[k * DHID + c];
      #pragma unroll
      for (int r = 0; r < 8; ++r) acc[r] = fmaf(hn[r][k], w, acc[r]);
    }
    #pragma unroll
    for (int r = 0; r < 8; ++r) Hx[(size_t)(i0 + r) * DHID + c] = f2bf(acc[r]);
  }
  if (t < DOUT) {
    int c = t;
    float acc[8];
    float b = bo[c];
    #pragma unroll
    for (int r = 0; r < 8; ++r) acc[r] = b;
    for (int k = 0; k < DIN; ++k) {
      float w = Wo[k * DOUT + c];
      #pragma unroll
      for (int r = 0; r < 8; ++r) acc[r] = fmaf(hn[r][k], w, acc[r]);
    }
    #pragma unroll
    for (int r = 0; r < 8; ++r) M2T[(size_t)c * N + i0 + r] = f2bf(acc[r]);
  }
}

// ---------------- K3: v = clip(sig(Hx Hx^T))*mask + I  (single pass) ----------------
// Coalesced ballot mask -> 2KB LDS bitmask; writes v (bf16 or f32) + row sums.
template <int BF16V>
__global__ __launch_bounds__(256) void smat(const unsigned short* __restrict__ Hx,
                     const float* __restrict__ A,
                     float* __restrict__ rowsum,
                     void* __restrict__ Vout) {
  __shared__ unsigned short la[128][LDP];
  __shared__ unsigned short lb[128][LDP];
  __shared__ unsigned long long mbt[128][2];
  int jt = blockIdx.x, it = blockIdx.y;
  int i0 = it * 128, j0 = jt * 128;
  int t = threadIdx.x;
  int w = t >> 6, l = t & 63;
  int lr = l & 15, lg = l >> 4;

  // --- mask fill: coalesced A reads + ballot -> LDS bitmask (low reg pressure) ---
  #pragma unroll 4
  for (int rr = 0; rr < 32; ++rr) {
    int row = w * 32 + rr;
    const float* Arow = &A[(size_t)(i0 + row) * N + j0 + l];
    float a0 = Arow[0];
    float a1 = Arow[64];
    unsigned long long b0 = __ballot(a0 > 0.f);
    unsigned long long b1 = __ballot(a1 > 0.f);
    if (l == 0) { mbt[row][0] = b0; mbt[row][1] = b1; }
  }

  f32x4 acc[2][8];
  f32x4 zero = {0.f, 0.f, 0.f, 0.f};
  #pragma unroll
  for (int m = 0; m < 2; ++m)
    #pragma unroll
    for (int n = 0; n < 8; ++n) acc[m][n] = zero;

  for (int c4 = 0; c4 < 4; ++c4) {
    int k0 = c4 * 64;
    __syncthreads();
    #pragma unroll
    for (int rp = 0; rp < 4; ++rp) {
      int row = rp * 32 + (t >> 3);
      int ch = (t & 7) * 8;
      *(short8*)&la[row][ch] = *(const short8*)&Hx[(size_t)(i0 + row) * DHID + k0 + ch];
      *(short8*)&lb[row][ch] = *(const short8*)&Hx[(size_t)(j0 + row) * DHID + k0 + ch];
    }
    __syncthreads();
    #pragma unroll
    for (int kk = 0; kk < 2; ++kk) {
      short8 af[2], bf[8];
      #pragma unroll
      for (int m = 0; m < 2; ++m)
        af[m] = *(const short8*)&la[w * 32 + m * 16 + lr][kk * 32 + lg * 8];
      #pragma unroll
      for (int n = 0; n < 8; ++n)
        bf[n] = *(const short8*)&lb[n * 16 + lr][kk * 32 + lg * 8];
      #pragma unroll
      for (int m = 0; m < 2; ++m)
        #pragma unroll
        for (int n = 0; n < 8; ++n)
          acc[m][n] = __builtin_amdgcn_mfma_f32_16x16x32_bf16(af[m], bf[n], acc[m][n], 0, 0, 0);
    }
  }

  #pragma unroll
  for (int m = 0; m < 2; ++m) {
    #pragma unroll
    for (int r = 0; r < 4; ++r) {
      int rl = w * 32 + m * 16 + lg * 4 + r;
      int gi = i0 + rl;
      unsigned long long w0 = mbt[rl][0], w1 = mbt[rl][1];
      float part = 0.f;
      #pragma unroll
      for (int n = 0; n < 8; ++n) {
        int gj = j0 + n * 16 + lr;
        int b = n * 16 + lr;
        float ms = (((n < 4 ? w0 : w1) >> (b & 63)) & 1ull) ? 1.f : 0.f;
        float v = sig_clip(acc[m][n][r]) * ms + (gi == gj ? 1.f : 0.f);
        part += v;
        if (BF16V)
          ((unsigned short*)Vout)[(size_t)gi * N + gj] = f2bf(v);
        else
          ((float*)Vout)[(size_t)gi * N + gj] = v;
      }
      part += __shfl_xor(part, 1);
      part += __shfl_xor(part, 2);
      part += __shfl_xor(part, 4);
      part += __shfl_xor(part, 8);
      if (lr == 0) atomicAdd(&rowsum[gi], part);
    }
  }
}

// ---------------- K3b: d = rsqrt(rowsum), in place ----------------
__global__ void dfin(float* rs) {
  int i = blockIdx.x * 256 + threadIdx.x;
  if (i < N) rs[i] = rsqrtf(rs[i]);
}

// ---------------- K4: fused scale + A_hat write + out = A_hat @ M2 ----------------
template <int BF16V>
__global__ __launch_bounds__(256) void outmm(const void* __restrict__ Vin,
                      const float* __restrict__ dd,
                      const unsigned short* __restrict__ M2T,
                      float* __restrict__ Ahat, float* __restrict__ out) {
  __shared__ unsigned short la[128][LDP];
  int kc = blockIdx.x;   // 0..15  (j-chunk of 512)
  int it = blockIdx.y;   // 0..63  (i-tile of 128)
  int i0 = it * 128;
  int jbase = kc * 512;
  int t = threadIdx.x;
  int w = t >> 6, l = t & 63;
  int lr = l & 15, lg = l >> 4;

  f32x4 acc[2][4];
  f32x4 zero = {0.f, 0.f, 0.f, 0.f};
  #pragma unroll
  for (int m = 0; m < 2; ++m)
    #pragma unroll
    for (int n = 0; n < 4; ++n) acc[m][n] = zero;

  for (int s = 0; s < 8; ++s) {
    int j0 = jbase + s * 64;
    __syncthreads();
    // stage v -> scale by di*dj -> write final f32 A_hat -> bf16 LDS
    #pragma unroll
    for (int rep = 0; rep < 8; ++rep) {
      int row = rep * 16 + (t >> 4);
      int cc = (t & 15) * 4;
      size_t idx = (size_t)(i0 + row) * N + j0 + cc;
      f32x4 v;
      if (BF16V) {
        u16x4 u = *(const u16x4*)&((const unsigned short*)Vin)[idx];
        v[0] = bf2f(u[0]); v[1] = bf2f(u[1]); v[2] = bf2f(u[2]); v[3] = bf2f(u[3]);
      } else {
        v = *(const f32x4*)&((const float*)Vin)[idx];
      }
      float di = dd[i0 + row];
      f32x4 dj = *(const f32x4*)&dd[j0 + cc];
      f32x4 sv;
      sv[0] = v[0] * di * dj[0]; sv[1] = v[1] * di * dj[1];
      sv[2] = v[2] * di * dj[2]; sv[3] = v[3] * di * dj[3];
      *(f32x4*)&Ahat[idx] = sv;
      u16x4 b;
      b[0] = f2bf(sv[0]); b[1] = f2bf(sv[1]); b[2] = f2bf(sv[2]); b[3] = f2bf(sv[3]);
      *(u16x4*)&la[row][cc] = b;
    }
    __syncthreads();
    #pragma unroll
    for (int kk = 0; kk < 2; ++kk) {
      short8 af[2], bfr[4];
      #pragma unroll
      for (int m = 0; m < 2; ++m)
        af[m] = *(const short8*)&la[w * 32 + m * 16 + lr][kk * 32 + lg * 8];
      #pragma unroll
      for (int n = 0; n < 4; ++n)
        bfr[n] = *(const short8*)&M2T[(size_t)(n * 16 + lr) * N + j0 + kk * 32 + lg * 8];
      #pragma unroll
      for (int m = 0; m < 2; ++m)
        #pragma unroll
        for (int n = 0; n < 4; ++n)
          acc[m][n] = __builtin_amdgcn_mfma_f32_16x16x32_bf16(af[m], bfr[n], acc[m][n], 0, 0, 0);
    }
  }
  #pragma unroll
  for (int m = 0; m < 2; ++m)
    #pragma unroll
    for (int n = 0; n < 4; ++n)
      #pragma unroll
      for (int r = 0; r < 4; ++r) {
        int gi = i0 + w * 32 + m * 16 + lg * 4 + r;
        int gc = n * 16 + lr;
        atomicAdd(&out[(size_t)gi * DOUT + gc], acc[m][n][r]);
      }
}

// ---------------- K5: LeakyReLU on out ----------------
__global__ void leaky(float* out) {
  int i = blockIdx.x * 256 + threadIdx.x;
  if (i < N * DOUT) {
    float x = out[i];
    out[i] = x >= 0.f ? x : 0.01f * x;
  }
}

extern "C" void kernel_launch(void* const* d_in, const int* in_sizes, int n_in,
                              void* d_out, int out_size, void* d_ws, size_t ws_size,
                              hipStream_t stream) {
  const float* H   = (const float*)d_in[0];
  const float* A   = (const float*)d_in[1];
  const float* bnw = (const float*)d_in[2];
  const float* bnb = (const float*)d_in[3];
  const float* Wt  = (const float*)d_in[4];
  const float* bt  = (const float*)d_in[5];
  const float* Wo  = (const float*)d_in[6];
  const float* bo  = (const float*)d_in[7];
  float* out = (float*)d_out;
  float* Ahat = out + (size_t)N * DOUT;

  char* ws = (char*)d_ws;
  float* scale  = (float*)(ws + 0);
  float* shift  = (float*)(ws + 512);
  float* rowsum = (float*)(ws + 4096);                    // 32 KB, becomes d after dfin
  unsigned short* M2T = (unsigned short*)(ws + 65536);    // 1 MB slot [64][N]
  unsigned short* Hx  = (unsigned short*)(ws + 2097152);  // 4 MB slot
  unsigned short* Vbf = (unsigned short*)(ws + (size_t)(8u << 20));  // 134 MB slot

  const size_t need_bf16 = (size_t)(8u << 20) + (size_t)N * N * 2;
  const bool big = ws_size >= need_bf16;

  hipMemsetAsync(rowsum, 0, N * sizeof(float), stream);
  hipMemsetAsync(out, 0, (size_t)N * DOUT * sizeof(float), stream);

  bn_stats<<<DIN, 256, 0, stream>>>(H, bnw, bnb, scale, shift);
  proj<<<N / 8, 256, 0, stream>>>(H, scale, shift, Wt, bt, Wo, bo, Hx, M2T);
  if (big) {
    smat<1><<<dim3(64, 64), 256, 0, stream>>>(Hx, A, rowsum, (void*)Vbf);
    dfin<<<N / 256, 256, 0, stream>>>(rowsum);
    outmm<1><<<dim3(16, 64), 256, 0, stream>>>((const void*)Vbf, rowsum, M2T, Ahat, out);
  } else {
    smat<0><<<dim3(64, 64), 256, 0, stream>>>(Hx, A, rowsum, (void*)Ahat);
    dfin<<<N / 256, 256, 0, stream>>>(rowsum);
    outmm<0><<<dim3(16, 64), 256, 0, stream>>>((const void*)Ahat, rowsum, M2T, Ahat, out);
  }
  leaky<<<(N * DOUT + 255) / 256, 256, 0, stream>>>(out);
}

// Round 4
// 367.010 us; speedup vs baseline: 1.2309x; 1.2309x over previous
//
#include <hip/hip_runtime.h>
#include <hip/hip_bf16.h>

#define N 8192
#define DIN 128
#define DHID 256
#define DOUT 64
#define LDP 72   // staging LDS row stride (ushorts)
#define VP 136   // V-epilogue LDS row stride (ushorts)

typedef __attribute__((ext_vector_type(8))) short short8;
typedef __attribute__((ext_vector_type(8))) unsigned short u16x8;
typedef __attribute__((ext_vector_type(4))) float f32x4;
typedef __attribute__((ext_vector_type(4))) unsigned short u16x4;

__device__ inline unsigned short f2bf(float x) {
  unsigned u = __float_as_uint(x);
  u += 0x7FFF + ((u >> 16) & 1);   // RNE
  return (unsigned short)(u >> 16);
}
__device__ inline float bf2f(unsigned short u) {
  return __uint_as_float(((unsigned)u) << 16);
}
__device__ inline float sig_clip(float x) {
  float s = 1.0f / (1.0f + __expf(-x));
  return fmaxf(s, 0.1f);
}

// ---------------- K0: pack (A>0) into interleaved bitmask, 8 MB ----------------
// Word layout: for 256-float aligned group g, word[g*4+e] bit l = (A[g*256+4l+e] > 0).
__global__ __launch_bounds__(256) void maskpack(const float* __restrict__ A,
                                                unsigned long long* __restrict__ Mb) {
  size_t i = (size_t)blockIdx.x * 256 + threadIdx.x;
  size_t step = (size_t)gridDim.x * 256;
  int l = threadIdx.x & 63;
  for (; i < (size_t)N * N / 4; i += step) {
    f32x4 a = *(const f32x4*)&A[i * 4];
    unsigned long long b0 = __ballot(a[0] > 0.f);
    unsigned long long b1 = __ballot(a[1] > 0.f);
    unsigned long long b2 = __ballot(a[2] > 0.f);
    unsigned long long b3 = __ballot(a[3] > 0.f);
    size_t g = (i - l) >> 6;
    if (l < 4) {
      unsigned long long bb = (l == 0) ? b0 : (l == 1) ? b1 : (l == 2) ? b2 : b3;
      Mb[g * 4 + l] = bb;
    }
  }
}

// ---------------- K1: BatchNorm statistics ----------------
__global__ void bn_stats(const float* __restrict__ H, const float* __restrict__ bnw,
                         const float* __restrict__ bnb, float* __restrict__ scale,
                         float* __restrict__ shift) {
  int f = blockIdx.x;
  int t = threadIdx.x;
  float s = 0.f, sq = 0.f;
  for (int r = t; r < N; r += 256) {
    float v = H[(size_t)r * DIN + f];
    s += v; sq += v * v;
  }
  __shared__ float ss[256], s2[256];
  ss[t] = s; s2[t] = sq;
  __syncthreads();
  for (int o = 128; o > 0; o >>= 1) {
    if (t < o) { ss[t] += ss[t + o]; s2[t] += s2[t + o]; }
    __syncthreads();
  }
  if (t == 0) {
    float mean = ss[0] * (1.0f / N);
    float var = s2[0] * (1.0f / N) - mean * mean;
    float sc = rsqrtf(var + 1e-5f) * bnw[f];
    scale[f] = sc;
    shift[f] = bnb[f] - mean * sc;
  }
}

// ---------------- K2: Hn -> Hx bf16 [N,256], M2T bf16 [64][N] ----------------
__global__ __launch_bounds__(256) void proj(const float* __restrict__ H,
                     const float* __restrict__ scale, const float* __restrict__ shift,
                     const float* __restrict__ Wt, const float* __restrict__ bt,
                     const float* __restrict__ Wo, const float* __restrict__ bo,
                     unsigned short* __restrict__ Hx, unsigned short* __restrict__ M2T) {
  __shared__ float hn[8][DIN];
  int i0 = blockIdx.x * 8;
  int t = threadIdx.x;
  #pragma unroll
  for (int rep = 0; rep < 4; ++rep) {
    int idx = rep * 256 + t;
    int r = idx >> 7, c = idx & 127;
    float h = H[(size_t)(i0 + r) * DIN + c];
    hn[r][c] = fmaf(h, scale[c], shift[c]);
  }
  __syncthreads();
  {
    int c = t;  // 0..255
    float acc[8];
    float b = bt[c];
    #pragma unroll
    for (int r = 0; r < 8; ++r) acc[r] = b;
    for (int k = 0; k < DIN; ++k) {
      float w = Wt[k * DHID + c];
      #pragma unroll
      for (int r = 0; r < 8; ++r) acc[r] = fmaf(hn[r][k], w, acc[r]);
    }
    #pragma unroll
    for (int r = 0; r < 8; ++r) Hx[(size_t)(i0 + r) * DHID + c] = f2bf(acc[r]);
  }
  if (t < DOUT) {
    int c = t;
    float acc[8];
    float b = bo[c];
    #pragma unroll
    for (int r = 0; r < 8; ++r) acc[r] = b;
    for (int k = 0; k < DIN; ++k) {
      float w = Wo[k * DOUT + c];
      #pragma unroll
      for (int r = 0; r < 8; ++r) acc[r] = fmaf(hn[r][k], w, acc[r]);
    }
    u16x8 v;
    #pragma unroll
    for (int r = 0; r < 8; ++r) v[r] = f2bf(acc[r]);
    *(u16x8*)&M2T[(size_t)c * N + i0] = v;
  }
}

// ---------------- K3: v = clip(sig(Hx Hx^T))*mask + I  (single pass) ----------------
template <int BF16V>
__global__ __launch_bounds__(256) void smat(const unsigned short* __restrict__ Hx,
                     const unsigned long long* __restrict__ Mb,
                     float* __restrict__ rowsum,
                     void* __restrict__ Vout) {
  __shared__ unsigned short lsh[2 * 128 * LDP];
  __shared__ unsigned mbt32[128][4];
  unsigned short* la = lsh;
  unsigned short* lb = lsh + 128 * LDP;
  int jt = blockIdx.x, it = blockIdx.y;
  int i0 = it * 128, j0 = jt * 128;
  int t = threadIdx.x;
  int w = t >> 6, l = t & 63;
  int lr = l & 15, lg = l >> 4;

  // mask bits for this tile: 128 rows x 32 used bits per word e=0..3
  if (t < 128) {
    const unsigned long long* src = &Mb[(size_t)(i0 + t) * (N / 64) + (j0 >> 8) * 4];
    int sh = (j0 & 128) ? 32 : 0;
    #pragma unroll
    for (int e = 0; e < 4; ++e)
      mbt32[t][e] = (unsigned)(src[e] >> sh);
  }

  f32x4 acc[2][8];
  f32x4 zero = {0.f, 0.f, 0.f, 0.f};
  #pragma unroll
  for (int m = 0; m < 2; ++m)
    #pragma unroll
    for (int n = 0; n < 8; ++n) acc[m][n] = zero;

  for (int c4 = 0; c4 < 4; ++c4) {
    int k0 = c4 * 64;
    __syncthreads();
    #pragma unroll
    for (int rp = 0; rp < 4; ++rp) {
      int row = rp * 32 + (t >> 3);
      int ch = (t & 7) * 8;
      *(short8*)&la[row * LDP + ch] = *(const short8*)&Hx[(size_t)(i0 + row) * DHID + k0 + ch];
      *(short8*)&lb[row * LDP + ch] = *(const short8*)&Hx[(size_t)(j0 + row) * DHID + k0 + ch];
    }
    __syncthreads();
    #pragma unroll
    for (int kk = 0; kk < 2; ++kk) {
      short8 af[2], bf[8];
      #pragma unroll
      for (int m = 0; m < 2; ++m)
        af[m] = *(const short8*)&la[(w * 32 + m * 16 + lr) * LDP + kk * 32 + lg * 8];
      #pragma unroll
      for (int n = 0; n < 8; ++n)
        bf[n] = *(const short8*)&lb[(n * 16 + lr) * LDP + kk * 32 + lg * 8];
      #pragma unroll
      for (int m = 0; m < 2; ++m)
        #pragma unroll
        for (int n = 0; n < 8; ++n)
          acc[m][n] = __builtin_amdgcn_mfma_f32_16x16x32_bf16(af[m], bf[n], acc[m][n], 0, 0, 0);
    }
  }

  if (BF16V) __syncthreads();  // about to overwrite lsh with the V tile

  #pragma unroll
  for (int m = 0; m < 2; ++m) {
    #pragma unroll
    for (int r = 0; r < 4; ++r) {
      int rl = w * 32 + m * 16 + lg * 4 + r;
      int gi = i0 + rl;
      unsigned mw = mbt32[rl][lr & 3];
      float part = 0.f;
      #pragma unroll
      for (int n = 0; n < 8; ++n) {
        int gj = j0 + n * 16 + lr;
        float ms = ((mw >> (n * 4 + (lr >> 2))) & 1u) ? 1.f : 0.f;
        float v = sig_clip(acc[m][n][r]) * ms + (gi == gj ? 1.f : 0.f);
        part += v;
        if (BF16V)
          lsh[rl * VP + n * 16 + lr] = f2bf(v);
        else
          ((float*)Vout)[(size_t)gi * N + gj] = v;
      }
      part += __shfl_xor(part, 1);
      part += __shfl_xor(part, 2);
      part += __shfl_xor(part, 4);
      part += __shfl_xor(part, 8);
      if (lr == 0) atomicAdd(&rowsum[gi], part);
    }
  }

  if (BF16V) {
    __syncthreads();
    #pragma unroll
    for (int pass = 0; pass < 8; ++pass) {
      int row = pass * 16 + (t >> 4);
      int cc = (t & 15) * 8;
      u16x8 vv = *(const u16x8*)&lsh[row * VP + cc];
      *(u16x8*)&((unsigned short*)Vout)[(size_t)(i0 + row) * N + j0 + cc] = vv;
    }
  }
}

// ---------------- K3b: d = rsqrt(rowsum), in place ----------------
__global__ void dfin(float* rs) {
  int i = blockIdx.x * 256 + threadIdx.x;
  if (i < N) rs[i] = rsqrtf(rs[i]);
}

// ---------------- K4: fused scale + A_hat write + out = A_hat @ M2 ----------------
template <int BF16V>
__global__ __launch_bounds__(256) void outmm(const void* __restrict__ Vin,
                      const float* __restrict__ dd,
                      const unsigned short* __restrict__ M2T,
                      float* __restrict__ Ahat, float* __restrict__ out) {
  __shared__ unsigned short la[128 * LDP];
  int kc = blockIdx.x;   // 0..15  (j-chunk of 512)
  int it = blockIdx.y;   // 0..63  (i-tile of 128)
  int i0 = it * 128;
  int jbase = kc * 512;
  int t = threadIdx.x;
  int w = t >> 6, l = t & 63;
  int lr = l & 15, lg = l >> 4;

  f32x4 acc[2][4];
  f32x4 zero = {0.f, 0.f, 0.f, 0.f};
  #pragma unroll
  for (int m = 0; m < 2; ++m)
    #pragma unroll
    for (int n = 0; n < 4; ++n) acc[m][n] = zero;

  for (int s = 0; s < 8; ++s) {
    int j0 = jbase + s * 64;
    __syncthreads();
    if (BF16V) {
      #pragma unroll
      for (int rep = 0; rep < 4; ++rep) {
        int row = rep * 32 + (t >> 3);
        int cc = (t & 7) * 8;
        size_t idx = (size_t)(i0 + row) * N + j0 + cc;
        u16x8 u = *(const u16x8*)&((const unsigned short*)Vin)[idx];
        float di = dd[i0 + row];
        f32x4 dj0 = *(const f32x4*)&dd[j0 + cc];
        f32x4 dj1 = *(const f32x4*)&dd[j0 + cc + 4];
        f32x4 s0, s1;
        s0[0] = bf2f(u[0]) * di * dj0[0]; s0[1] = bf2f(u[1]) * di * dj0[1];
        s0[2] = bf2f(u[2]) * di * dj0[2]; s0[3] = bf2f(u[3]) * di * dj0[3];
        s1[0] = bf2f(u[4]) * di * dj1[0]; s1[1] = bf2f(u[5]) * di * dj1[1];
        s1[2] = bf2f(u[6]) * di * dj1[2]; s1[3] = bf2f(u[7]) * di * dj1[3];
        *(f32x4*)&Ahat[idx] = s0;
        *(f32x4*)&Ahat[idx + 4] = s1;
        u16x8 b;
        b[0] = f2bf(s0[0]); b[1] = f2bf(s0[1]); b[2] = f2bf(s0[2]); b[3] = f2bf(s0[3]);
        b[4] = f2bf(s1[0]); b[5] = f2bf(s1[1]); b[6] = f2bf(s1[2]); b[7] = f2bf(s1[3]);
        *(u16x8*)&la[row * LDP + cc] = b;
      }
    } else {
      #pragma unroll
      for (int rep = 0; rep < 8; ++rep) {
        int row = rep * 16 + (t >> 4);
        int cc = (t & 15) * 4;
        size_t idx = (size_t)(i0 + row) * N + j0 + cc;
        f32x4 v = *(const f32x4*)&((const float*)Vin)[idx];
        float di = dd[i0 + row];
        f32x4 dj = *(const f32x4*)&dd[j0 + cc];
        f32x4 sv;
        sv[0] = v[0] * di * dj[0]; sv[1] = v[1] * di * dj[1];
        sv[2] = v[2] * di * dj[2]; sv[3] = v[3] * di * dj[3];
        *(f32x4*)&Ahat[idx] = sv;
        u16x4 b;
        b[0] = f2bf(sv[0]); b[1] = f2bf(sv[1]); b[2] = f2bf(sv[2]); b[3] = f2bf(sv[3]);
        *(u16x4*)&la[row * LDP + cc] = b;
      }
    }
    __syncthreads();
    #pragma unroll
    for (int kk = 0; kk < 2; ++kk) {
      short8 af[2], bfr[4];
      #pragma unroll
      for (int m = 0; m < 2; ++m)
        af[m] = *(const short8*)&la[(w * 32 + m * 16 + lr) * LDP + kk * 32 + lg * 8];
      #pragma unroll
      for (int n = 0; n < 4; ++n)
        bfr[n] = *(const short8*)&M2T[(size_t)(n * 16 + lr) * N + j0 + kk * 32 + lg * 8];
      #pragma unroll
      for (int m = 0; m < 2; ++m)
        #pragma unroll
        for (int n = 0; n < 4; ++n)
          acc[m][n] = __builtin_amdgcn_mfma_f32_16x16x32_bf16(af[m], bfr[n], acc[m][n], 0, 0, 0);
    }
  }
  #pragma unroll
  for (int m = 0; m < 2; ++m)
    #pragma unroll
    for (int n = 0; n < 4; ++n)
      #pragma unroll
      for (int r = 0; r < 4; ++r) {
        int gi = i0 + w * 32 + m * 16 + lg * 4 + r;
        int gc = n * 16 + lr;
        atomicAdd(&out[(size_t)gi * DOUT + gc], acc[m][n][r]);
      }
}

// ---------------- K5: LeakyReLU on out ----------------
__global__ void leaky(float* out) {
  int i = blockIdx.x * 256 + threadIdx.x;
  if (i < N * DOUT) {
    float x = out[i];
    out[i] = x >= 0.f ? x : 0.01f * x;
  }
}

extern "C" void kernel_launch(void* const* d_in, const int* in_sizes, int n_in,
                              void* d_out, int out_size, void* d_ws, size_t ws_size,
                              hipStream_t stream) {
  const float* H   = (const float*)d_in[0];
  const float* A   = (const float*)d_in[1];
  const float* bnw = (const float*)d_in[2];
  const float* bnb = (const float*)d_in[3];
  const float* Wt  = (const float*)d_in[4];
  const float* bt  = (const float*)d_in[5];
  const float* Wo  = (const float*)d_in[6];
  const float* bo  = (const float*)d_in[7];
  float* out = (float*)d_out;
  float* Ahat = out + (size_t)N * DOUT;

  char* ws = (char*)d_ws;
  float* scale  = (float*)(ws + 0);
  float* shift  = (float*)(ws + 512);
  float* rowsum = (float*)(ws + 4096);                    // 32 KB, becomes d after dfin
  unsigned short* M2T = (unsigned short*)(ws + 65536);    // 1 MB slot [64][N]
  unsigned short* Hx  = (unsigned short*)(ws + 2097152);  // 4 MB slot
  unsigned long long* Mb = (unsigned long long*)(ws + (size_t)(6u << 20));  // 8 MB bitmask
  unsigned short* Vbf = (unsigned short*)(ws + (size_t)(14u << 20));        // 134 MB slot

  const size_t need_bf16 = ((size_t)14 << 20) + (size_t)N * N * 2;
  const bool big = ws_size >= need_bf16;

  hipMemsetAsync(rowsum, 0, N * sizeof(float), stream);
  hipMemsetAsync(out, 0, (size_t)N * DOUT * sizeof(float), stream);

  maskpack<<<4096, 256, 0, stream>>>(A, Mb);
  bn_stats<<<DIN, 256, 0, stream>>>(H, bnw, bnb, scale, shift);
  proj<<<N / 8, 256, 0, stream>>>(H, scale, shift, Wt, bt, Wo, bo, Hx, M2T);
  if (big) {
    smat<1><<<dim3(64, 64), 256, 0, stream>>>(Hx, Mb, rowsum, (void*)Vbf);
    dfin<<<N / 256, 256, 0, stream>>>(rowsum);
    outmm<1><<<dim3(16, 64), 256, 0, stream>>>((const void*)Vbf, rowsum, M2T, Ahat, out);
  } else {
    smat<0><<<dim3(64, 64), 256, 0, stream>>>(Hx, Mb, rowsum, (void*)Ahat);
    dfin<<<N / 256, 256, 0, stream>>>(rowsum);
    outmm<0><<<dim3(16, 64), 256, 0, stream>>>((const void*)Ahat, rowsum, M2T, Ahat, out);
  }
  leaky<<<(N * DOUT + 255) / 256, 256, 0, stream>>>(out);
}

// Round 5
// 331.033 us; speedup vs baseline: 1.3647x; 1.1087x over previous
//
#include <hip/hip_runtime.h>
#include <hip/hip_bf16.h>

#define N 8192
#define DIN 128
#define DHID 256
#define DOUT 64
#define LDP 72   // outmm staging LDS row stride (ushorts)
#define VP 136   // V-epilogue LDS row stride (ushorts)

typedef __attribute__((ext_vector_type(8))) short short8;
typedef __attribute__((ext_vector_type(8))) unsigned short u16x8;
typedef __attribute__((ext_vector_type(4))) float f32x4;
typedef __attribute__((ext_vector_type(4))) unsigned short u16x4;

typedef __attribute__((address_space(1))) const unsigned int GlbU32;
typedef __attribute__((address_space(3))) unsigned int LdsU32;

__device__ inline void gload16(const void* g, void* l) {
  __builtin_amdgcn_global_load_lds((GlbU32*)g, (LdsU32*)l, 16, 0, 0);
}

__device__ inline unsigned short f2bf(float x) {
  unsigned u = __float_as_uint(x);
  u += 0x7FFF + ((u >> 16) & 1);   // RNE
  return (unsigned short)(u >> 16);
}
__device__ inline float bf2f(unsigned short u) {
  return __uint_as_float(((unsigned)u) << 16);
}
__device__ inline float sig_clip(float x) {
  float s = 1.0f / (1.0f + __expf(-x));
  return fmaxf(s, 0.1f);
}

// ---------------- K0: pack (A>0) into interleaved bitmask, 8 MB ----------------
__global__ __launch_bounds__(256) void maskpack(const float* __restrict__ A,
                                                unsigned long long* __restrict__ Mb) {
  size_t i = (size_t)blockIdx.x * 256 + threadIdx.x;
  size_t step = (size_t)gridDim.x * 256;
  int l = threadIdx.x & 63;
  for (; i < (size_t)N * N / 4; i += step) {
    f32x4 a = *(const f32x4*)&A[i * 4];
    unsigned long long b0 = __ballot(a[0] > 0.f);
    unsigned long long b1 = __ballot(a[1] > 0.f);
    unsigned long long b2 = __ballot(a[2] > 0.f);
    unsigned long long b3 = __ballot(a[3] > 0.f);
    size_t g = (i - l) >> 6;
    if (l < 4) {
      unsigned long long bb = (l == 0) ? b0 : (l == 1) ? b1 : (l == 2) ? b2 : b3;
      Mb[g * 4 + l] = bb;
    }
  }
}

// ---------------- K1: BatchNorm statistics ----------------
__global__ void bn_stats(const float* __restrict__ H, const float* __restrict__ bnw,
                         const float* __restrict__ bnb, float* __restrict__ scale,
                         float* __restrict__ shift) {
  int f = blockIdx.x;
  int t = threadIdx.x;
  float s = 0.f, sq = 0.f;
  for (int r = t; r < N; r += 256) {
    float v = H[(size_t)r * DIN + f];
    s += v; sq += v * v;
  }
  __shared__ float ss[256], s2[256];
  ss[t] = s; s2[t] = sq;
  __syncthreads();
  for (int o = 128; o > 0; o >>= 1) {
    if (t < o) { ss[t] += ss[t + o]; s2[t] += s2[t + o]; }
    __syncthreads();
  }
  if (t == 0) {
    float mean = ss[0] * (1.0f / N);
    float var = s2[0] * (1.0f / N) - mean * mean;
    float sc = rsqrtf(var + 1e-5f) * bnw[f];
    scale[f] = sc;
    shift[f] = bnb[f] - mean * sc;
  }
}

// ---------------- K2: Hn -> Hx bf16 [N,256], M2T bf16 [64][N] ----------------
__global__ __launch_bounds__(256) void proj(const float* __restrict__ H,
                     const float* __restrict__ scale, const float* __restrict__ shift,
                     const float* __restrict__ Wt, const float* __restrict__ bt,
                     const float* __restrict__ Wo, const float* __restrict__ bo,
                     unsigned short* __restrict__ Hx, unsigned short* __restrict__ M2T) {
  __shared__ float hn[8][DIN];
  int i0 = blockIdx.x * 8;
  int t = threadIdx.x;
  #pragma unroll
  for (int rep = 0; rep < 4; ++rep) {
    int idx = rep * 256 + t;
    int r = idx >> 7, c = idx & 127;
    float h = H[(size_t)(i0 + r) * DIN + c];
    hn[r][c] = fmaf(h, scale[c], shift[c]);
  }
  __syncthreads();
  {
    int c = t;  // 0..255
    float acc[8];
    float b = bt[c];
    #pragma unroll
    for (int r = 0; r < 8; ++r) acc[r] = b;
    for (int k = 0; k < DIN; ++k) {
      float w = Wt[k * DHID + c];
      #pragma unroll
      for (int r = 0; r < 8; ++r) acc[r] = fmaf(hn[r][k], w, acc[r]);
    }
    #pragma unroll
    for (int r = 0; r < 8; ++r) Hx[(size_t)(i0 + r) * DHID + c] = f2bf(acc[r]);
  }
  if (t < DOUT) {
    int c = t;
    float acc[8];
    float b = bo[c];
    #pragma unroll
    for (int r = 0; r < 8; ++r) acc[r] = b;
    for (int k = 0; k < DIN; ++k) {
      float w = Wo[k * DOUT + c];
      #pragma unroll
      for (int r = 0; r < 8; ++r) acc[r] = fmaf(hn[r][k], w, acc[r]);
    }
    u16x8 v;
    #pragma unroll
    for (int r = 0; r < 8; ++r) v[r] = f2bf(acc[r]);
    *(u16x8*)&M2T[(size_t)c * N + i0] = v;
  }
}

// ---------------- K3: v = clip(sig(Hx Hx^T))*mask + I  (m97-structure K-loop) ----------------
// LDS tiles [128][64] linear (global_load_lds), source-col pre-swizzled with
// group^(row&7); ds_read uses the same involution -> conflict-free fragments.
template <int BF16V>
__global__ __launch_bounds__(256) void smat(const unsigned short* __restrict__ Hx,
                     const unsigned long long* __restrict__ Mb,
                     float* __restrict__ rowsum,
                     void* __restrict__ Vout) {
  __shared__ unsigned short lsh[17408];     // staging: la[0..8191], lb[8192..16383]; V tile: [128][VP]
  __shared__ unsigned mbt32[128][4];
  unsigned short* la = lsh;
  unsigned short* lb = lsh + 8192;
  int jt = blockIdx.x, it = blockIdx.y;
  int i0 = it * 128, j0 = jt * 128;
  int t = threadIdx.x;
  int w = t >> 6, l = t & 63;
  int lr = l & 15, lg = l >> 4;

  // mask bits for this tile: 128 rows x 32 used bits per word e=0..3
  if (t < 128) {
    const unsigned long long* src = &Mb[(size_t)(i0 + t) * (N / 64) + (j0 >> 8) * 4];
    int sh = (j0 & 128) ? 32 : 0;
    #pragma unroll
    for (int e = 0; e < 4; ++e)
      mbt32[t][e] = (unsigned)(src[e] >> sh);
  }

  f32x4 acc[2][8];
  f32x4 zero = {0.f, 0.f, 0.f, 0.f};
  #pragma unroll
  for (int m = 0; m < 2; ++m)
    #pragma unroll
    for (int n = 0; n < 8; ++n) acc[m][n] = zero;

  // per-lane swizzled source column (u16 units) and per-thread fragment swizzle
  const int srow = l >> 3;                 // row within 8-row chunk
  const int scol = ((l & 7) ^ srow) * 8;   // pre-swizzled global col group
  const int fswz = (lr & 7) * 8;           // fragment-read XOR (row&7)*8

  for (int c4 = 0; c4 < 4; ++c4) {
    int k0 = c4 * 64;
    __syncthreads();                        // previous tile fully consumed
    #pragma unroll
    for (int rp = 0; rp < 4; ++rp) {
      int chunk = rp * 4 + w;               // 0..15, wave-uniform LDS base
      int row = chunk * 8 + srow;
      gload16(&Hx[(size_t)(i0 + row) * DHID + k0 + scol], &la[chunk * 512]);
      gload16(&Hx[(size_t)(j0 + row) * DHID + k0 + scol], &lb[chunk * 512]);
    }
    __syncthreads();                        // compiler drains vmcnt(0) here
    #pragma unroll
    for (int kk = 0; kk < 2; ++kk) {
      int c = (kk * 32 + lg * 8) ^ fswz;
      short8 af[2], bf[8];
      #pragma unroll
      for (int m = 0; m < 2; ++m)
        af[m] = *(const short8*)&la[(w * 32 + m * 16 + lr) * 64 + c];
      #pragma unroll
      for (int n = 0; n < 8; ++n)
        bf[n] = *(const short8*)&lb[(n * 16 + lr) * 64 + c];
      #pragma unroll
      for (int m = 0; m < 2; ++m)
        #pragma unroll
        for (int n = 0; n < 8; ++n)
          acc[m][n] = __builtin_amdgcn_mfma_f32_16x16x32_bf16(af[m], bf[n], acc[m][n], 0, 0, 0);
    }
  }

  if (BF16V) __syncthreads();  // about to overwrite lsh with the V tile

  #pragma unroll
  for (int m = 0; m < 2; ++m) {
    #pragma unroll
    for (int r = 0; r < 4; ++r) {
      int rl = w * 32 + m * 16 + lg * 4 + r;
      int gi = i0 + rl;
      unsigned mw = mbt32[rl][lr & 3];
      float part = 0.f;
      #pragma unroll
      for (int n = 0; n < 8; ++n) {
        int gj = j0 + n * 16 + lr;
        float ms = ((mw >> (n * 4 + (lr >> 2))) & 1u) ? 1.f : 0.f;
        float v = sig_clip(acc[m][n][r]) * ms + (gi == gj ? 1.f : 0.f);
        part += v;
        if (BF16V)
          lsh[rl * VP + n * 16 + lr] = f2bf(v);
        else
          ((float*)Vout)[(size_t)gi * N + gj] = v;
      }
      part += __shfl_xor(part, 1);
      part += __shfl_xor(part, 2);
      part += __shfl_xor(part, 4);
      part += __shfl_xor(part, 8);
      if (lr == 0) atomicAdd(&rowsum[gi], part);
    }
  }

  if (BF16V) {
    __syncthreads();
    #pragma unroll
    for (int pass = 0; pass < 8; ++pass) {
      int row = pass * 16 + (t >> 4);
      int cc = (t & 15) * 8;
      u16x8 vv = *(const u16x8*)&lsh[row * VP + cc];
      *(u16x8*)&((unsigned short*)Vout)[(size_t)(i0 + row) * N + j0 + cc] = vv;
    }
  }
}

// ---------------- K3b: d = rsqrt(rowsum), in place ----------------
__global__ void dfin(float* rs) {
  int i = blockIdx.x * 256 + threadIdx.x;
  if (i < N) rs[i] = rsqrtf(rs[i]);
}

// ---------------- K4: fused scale + A_hat write + out = A_hat @ M2 ----------------
template <int BF16V>
__global__ __launch_bounds__(256) void outmm(const void* __restrict__ Vin,
                      const float* __restrict__ dd,
                      const unsigned short* __restrict__ M2T,
                      float* __restrict__ Ahat, float* __restrict__ out) {
  __shared__ unsigned short la[128 * LDP];
  int kc = blockIdx.x;   // 0..15  (j-chunk of 512)
  int it = blockIdx.y;   // 0..63  (i-tile of 128)
  int i0 = it * 128;
  int jbase = kc * 512;
  int t = threadIdx.x;
  int w = t >> 6, l = t & 63;
  int lr = l & 15, lg = l >> 4;

  f32x4 acc[2][4];
  f32x4 zero = {0.f, 0.f, 0.f, 0.f};
  #pragma unroll
  for (int m = 0; m < 2; ++m)
    #pragma unroll
    for (int n = 0; n < 4; ++n) acc[m][n] = zero;

  for (int s = 0; s < 8; ++s) {
    int j0 = jbase + s * 64;
    __syncthreads();
    if (BF16V) {
      #pragma unroll
      for (int rep = 0; rep < 4; ++rep) {
        int row = rep * 32 + (t >> 3);
        int cc = (t & 7) * 8;
        size_t idx = (size_t)(i0 + row) * N + j0 + cc;
        u16x8 u = *(const u16x8*)&((const unsigned short*)Vin)[idx];
        float di = dd[i0 + row];
        f32x4 dj0 = *(const f32x4*)&dd[j0 + cc];
        f32x4 dj1 = *(const f32x4*)&dd[j0 + cc + 4];
        f32x4 s0, s1;
        s0[0] = bf2f(u[0]) * di * dj0[0]; s0[1] = bf2f(u[1]) * di * dj0[1];
        s0[2] = bf2f(u[2]) * di * dj0[2]; s0[3] = bf2f(u[3]) * di * dj0[3];
        s1[0] = bf2f(u[4]) * di * dj1[0]; s1[1] = bf2f(u[5]) * di * dj1[1];
        s1[2] = bf2f(u[6]) * di * dj1[2]; s1[3] = bf2f(u[7]) * di * dj1[3];
        *(f32x4*)&Ahat[idx] = s0;
        *(f32x4*)&Ahat[idx + 4] = s1;
        u16x8 b;
        b[0] = f2bf(s0[0]); b[1] = f2bf(s0[1]); b[2] = f2bf(s0[2]); b[3] = f2bf(s0[3]);
        b[4] = f2bf(s1[0]); b[5] = f2bf(s1[1]); b[6] = f2bf(s1[2]); b[7] = f2bf(s1[3]);
        *(u16x8*)&la[row * LDP + cc] = b;
      }
    } else {
      #pragma unroll
      for (int rep = 0; rep < 8; ++rep) {
        int row = rep * 16 + (t >> 4);
        int cc = (t & 15) * 4;
        size_t idx = (size_t)(i0 + row) * N + j0 + cc;
        f32x4 v = *(const f32x4*)&((const float*)Vin)[idx];
        float di = dd[i0 + row];
        f32x4 dj = *(const f32x4*)&dd[j0 + cc];
        f32x4 sv;
        sv[0] = v[0] * di * dj[0]; sv[1] = v[1] * di * dj[1];
        sv[2] = v[2] * di * dj[2]; sv[3] = v[3] * di * dj[3];
        *(f32x4*)&Ahat[idx] = sv;
        u16x4 b;
        b[0] = f2bf(sv[0]); b[1] = f2bf(sv[1]); b[2] = f2bf(sv[2]); b[3] = f2bf(sv[3]);
        *(u16x4*)&la[row * LDP + cc] = b;
      }
    }
    __syncthreads();
    #pragma unroll
    for (int kk = 0; kk < 2; ++kk) {
      short8 af[2], bfr[4];
      #pragma unroll
      for (int m = 0; m < 2; ++m)
        af[m] = *(const short8*)&la[(w * 32 + m * 16 + lr) * LDP + kk * 32 + lg * 8];
      #pragma unroll
      for (int n = 0; n < 4; ++n)
        bfr[n] = *(const short8*)&M2T[(size_t)(n * 16 + lr) * N + j0 + kk * 32 + lg * 8];
      #pragma unroll
      for (int m = 0; m < 2; ++m)
        #pragma unroll
        for (int n = 0; n < 4; ++n)
          acc[m][n] = __builtin_amdgcn_mfma_f32_16x16x32_bf16(af[m], bfr[n], acc[m][n], 0, 0, 0);
    }
  }
  #pragma unroll
  for (int m = 0; m < 2; ++m)
    #pragma unroll
    for (int n = 0; n < 4; ++n)
      #pragma unroll
      for (int r = 0; r < 4; ++r) {
        int gi = i0 + w * 32 + m * 16 + lg * 4 + r;
        int gc = n * 16 + lr;
        atomicAdd(&out[(size_t)gi * DOUT + gc], acc[m][n][r]);
      }
}

// ---------------- K5: LeakyReLU on out ----------------
__global__ void leaky(float* out) {
  int i = blockIdx.x * 256 + threadIdx.x;
  if (i < N * DOUT) {
    float x = out[i];
    out[i] = x >= 0.f ? x : 0.01f * x;
  }
}

extern "C" void kernel_launch(void* const* d_in, const int* in_sizes, int n_in,
                              void* d_out, int out_size, void* d_ws, size_t ws_size,
                              hipStream_t stream) {
  const float* H   = (const float*)d_in[0];
  const float* A   = (const float*)d_in[1];
  const float* bnw = (const float*)d_in[2];
  const float* bnb = (const float*)d_in[3];
  const float* Wt  = (const float*)d_in[4];
  const float* bt  = (const float*)d_in[5];
  const float* Wo  = (const float*)d_in[6];
  const float* bo  = (const float*)d_in[7];
  float* out = (float*)d_out;
  float* Ahat = out + (size_t)N * DOUT;

  char* ws = (char*)d_ws;
  float* scale  = (float*)(ws + 0);
  float* shift  = (float*)(ws + 512);
  float* rowsum = (float*)(ws + 4096);                    // 32 KB, becomes d after dfin
  unsigned short* M2T = (unsigned short*)(ws + 65536);    // 1 MB slot [64][N]
  unsigned short* Hx  = (unsigned short*)(ws + 2097152);  // 4 MB slot
  unsigned long long* Mb = (unsigned long long*)(ws + (size_t)(6u << 20));  // 8 MB bitmask
  unsigned short* Vbf = (unsigned short*)(ws + (size_t)(14u << 20));        // 134 MB slot

  const size_t need_bf16 = ((size_t)14 << 20) + (size_t)N * N * 2;
  const bool big = ws_size >= need_bf16;

  hipMemsetAsync(rowsum, 0, N * sizeof(float), stream);
  hipMemsetAsync(out, 0, (size_t)N * DOUT * sizeof(float), stream);

  maskpack<<<4096, 256, 0, stream>>>(A, Mb);
  bn_stats<<<DIN, 256, 0, stream>>>(H, bnw, bnb, scale, shift);
  proj<<<N / 8, 256, 0, stream>>>(H, scale, shift, Wt, bt, Wo, bo, Hx, M2T);
  if (big) {
    smat<1><<<dim3(64, 64), 256, 0, stream>>>(Hx, Mb, rowsum, (void*)Vbf);
    dfin<<<N / 256, 256, 0, stream>>>(rowsum);
    outmm<1><<<dim3(16, 64), 256, 0, stream>>>((const void*)Vbf, rowsum, M2T, Ahat, out);
  } else {
    smat<0><<<dim3(64, 64), 256, 0, stream>>>(Hx, Mb, rowsum, (void*)Ahat);
    dfin<<<N / 256, 256, 0, stream>>>(rowsum);
    outmm<0><<<dim3(16, 64), 256, 0, stream>>>((const void*)Ahat, rowsum, M2T, Ahat, out);
  }
  leaky<<<(N * DOUT + 255) / 256, 256, 0, stream>>>(out);
}